// Round 20
// baseline (122.959 us; speedup 1.0000x reference)
//
#include <hip/hip_runtime.h>
#include <hip/hip_bf16.h>

typedef __hip_bfloat16 bf16;
typedef __attribute__((ext_vector_type(8))) short s8v;
typedef __attribute__((ext_vector_type(4))) float f32x4;

#define DM 512
#define NH 8
#define DKH 64
#define DFF 2048
#define NB 2
#define NS 2048
#define NR (NB*NS)
#define LN_EPS 1e-6f
#define NEG_BIG (-1e30f)
#define LDQKV (3*DM)
// fixed-shift softmax (natural domain): P = exp(s*0.125 - 6), exact softmax
// numerator by shift-invariance; masked -> exp(-1e30) = 0.
#define SM_SHIFT (-6.0f)
#define PART_ELEMS (NB*NH*NS*DKH)    /* 2097152 */

#define MFMA_B16(a,b,c) __builtin_amdgcn_mfma_f32_16x16x32_bf16(a,b,c,0,0,0)

#define GLOAD16(g, l) __builtin_amdgcn_global_load_lds( \
    (const __attribute__((address_space(1))) void*)(g), \
    (__attribute__((address_space(3))) void*)(l), 16, 0, 0)

__device__ __forceinline__ float us2f(unsigned int u){ return __uint_as_float(u << 16); }
__device__ __forceinline__ float b2f(bf16 v){ return __bfloat162float(v); }
__device__ __forceinline__ float ldf(const float* p){ return *p; }
__device__ __forceinline__ float ldf(const bf16* p){ return __bfloat162float(*p); }
__device__ __forceinline__ void stf(float* p, float v){ *p = v; }
__device__ __forceinline__ void stf(bf16* p, float v){ *p = __float2bfloat16(v); }
__device__ __forceinline__ unsigned short f2bu(float f){
  bf16 b = __float2bfloat16(f);
  return *reinterpret_cast<unsigned short*>(&b);
}

template<int N> __device__ __forceinline__ void waitcnt_vm(){
  if constexpr(N==0)      asm volatile("s_waitcnt vmcnt(0)" ::: "memory");
  else if constexpr(N==2) asm volatile("s_waitcnt vmcnt(2)" ::: "memory");
  else if constexpr(N==3) asm volatile("s_waitcnt vmcnt(3)" ::: "memory");
  else if constexpr(N==4) asm volatile("s_waitcnt vmcnt(4)" ::: "memory");
  else if constexpr(N==5) asm volatile("s_waitcnt vmcnt(5)" ::: "memory");
  else if constexpr(N==6) asm volatile("s_waitcnt vmcnt(6)" ::: "memory");
  else if constexpr(N==8) asm volatile("s_waitcnt vmcnt(8)" ::: "memory");
}

// swizzled byte offset of element (row, col-byte) in a 128B-row LDS tile
__device__ __forceinline__ int swz(int row, int colbyte){
  return ((row<<7) + colbyte) ^ ((row&7)<<4);
}

__device__ __forceinline__ float wsum(float v){
#pragma unroll
  for(int o=32;o>0;o>>=1) v += __shfl_down(v,o,64);
  return v;
}

// ---- tile staging: R rows x 64 bf16 cols -> swizzled LDS.
// NTHR-generic: chunk c = tid + k*NTHR keeps wave-uniform base + lane*16.
template<int NTHR>
__device__ __forceinline__ void stage_tile(char* lds, const bf16* g, int ld, int R, int tid){
  int nch = R*8;
  for(int c = tid; c < nch; c += NTHR){
    int row = c>>3;
    int blk = (c&7) ^ (row&7);
    GLOAD16(g + (size_t)row*ld + blk*8, lds + c*16);
  }
}
__device__ __forceinline__ s8v read_frag(const char* lds, int row, int col){
  return *reinterpret_cast<const s8v*>(lds + swz(row, col<<1));
}

// ---- prep: batched weight transpose+convert (blocks 0..767) AND LN1
// (blocks 768..4863, one row each) in a single launch.
__global__ __launch_bounds__(256) void prep_kernel(
    const float* __restrict__ Wq, const float* __restrict__ Wk,
    const float* __restrict__ Wv, const float* __restrict__ Wo,
    const float* __restrict__ W1, const float* __restrict__ W2,
    bf16* __restrict__ WTqkv, bf16* __restrict__ WTo,
    bf16* __restrict__ WT1, bf16* __restrict__ WT2,
    const float* __restrict__ x, bf16* __restrict__ h1,
    const float* __restrict__ ap, const float* __restrict__ bp){
  __shared__ float t[64][65];
  __shared__ float s1[4], s2[4];
  int tid = threadIdx.x;
  if(blockIdx.x >= 768){
    // ---- LayerNorm row (unbiased var /511, eps added to std)
    int row = blockIdx.x - 768;
    const float* xr = x + (size_t)row*DM;
    float v0 = xr[tid], v1 = xr[tid+256];
    float s = wsum(v0+v1);
    float q = wsum(v0*v0+v1*v1);
    int wid = tid>>6, lane = tid&63;
    if(lane==0){ s1[wid]=s; s2[wid]=q; }
    __syncthreads();
    float S = s1[0]+s1[1]+s1[2]+s1[3];
    float Q = s2[0]+s2[1]+s2[2]+s2[3];
    float mean = S*(1.f/DM);
    float var  = (Q - (float)DM*mean*mean)*(1.f/(DM-1));
    float sd   = sqrtf(fmaxf(var,0.f));
    float sc = (*ap)/(sd+LN_EPS);
    float b = *bp;
    bf16* orow = h1 + (size_t)row*DM;
    orow[tid]     = __float2bfloat16((v0-mean)*sc + b);
    orow[tid+256] = __float2bfloat16((v1-mean)*sc + b);
    return;
  }
  int tb = blockIdx.x;
  const float* W; bf16* WT; int K, N, nx;
  if(tb < 192){
    int w = tb>>6; tb &= 63;
    W = (w==0)?Wq:(w==1)?Wk:Wv; WT = WTqkv + w*512*512; K=512; N=512; nx=8;
  } else if(tb < 256){ tb -= 192; W=Wo; WT=WTo; K=512; N=512; nx=8; }
  else if(tb < 512){ tb -= 256; W=W1; WT=WT1; K=512; N=2048; nx=32; }
  else { tb -= 512; W=W2; WT=WT2; K=2048; N=512; nx=8; }
  int n0 = (tb % nx)*64, k0 = (tb / nx)*64;
  int rr = tid>>6, cc = tid&63;
#pragma unroll
  for(int r=rr;r<64;r+=4) t[r][cc] = W[(size_t)(k0+r)*N + n0+cc];
  __syncthreads();
#pragma unroll
  for(int r=rr;r<64;r+=4) WT[(size_t)(n0+r)*K + k0+cc] = __float2bfloat16(t[cc][r]);
}

// ---- LayerNorm over bf16 rows, wave-per-row vectorized (16B load/store per lane)
__global__ __launch_bounds__(256) void ln4_kernel(const bf16* __restrict__ x,
    bf16* __restrict__ out, const float* __restrict__ ap, const float* __restrict__ bp){
  int tid = threadIdx.x, wave = tid>>6, lane = tid&63;
  int row = blockIdx.x*4 + wave;
  const bf16* xr = x + (size_t)row*DM + lane*8;
  s8v v = *reinterpret_cast<const s8v*>(xr);
  float f[8];
  float s = 0.f, q = 0.f;
#pragma unroll
  for(int j=0;j<8;j++){
    f[j] = us2f((unsigned short)v[j]);
    s += f[j]; q += f[j]*f[j];
  }
  s = wsum(s); q = wsum(q);
  s = __shfl(s, 0, 64); q = __shfl(q, 0, 64);
  float mean = s*(1.f/DM);
  float var  = (q - (float)DM*mean*mean)*(1.f/(DM-1));
  float sd   = sqrtf(fmaxf(var,0.f));
  float sc = (*ap)/(sd+LN_EPS);
  float b = *bp;
  s8v o;
#pragma unroll
  for(int j=0;j<8;j++) o[j] = (short)f2bu((f[j]-mean)*sc + b);
  *reinterpret_cast<s8v*>(out + (size_t)row*DM + lane*8) = o;
}

// ---- MFMA GEMM: C[m][n] = A[m][k] * WT[n][k] + bias (+resid) (+relu)
// 4 waves, tile BM x BN, BK=64, dbuf LDS + counted vmcnt (never drain mid-loop).
// QKVSEL=1: cols [1024,1536) (the V projection) are written DIRECTLY to
// VT [b][h][d][k'] with the k-permutation kp=((k&15)+r)*4+(k>>4).
template<int BM, int BN, int RELU, int QKVSEL, typename TR, typename TO>
__global__ __launch_bounds__(256) void mfma_gemm(
    const bf16* __restrict__ A, const bf16* __restrict__ WT,
    const float* __restrict__ bias0, const float* __restrict__ bias1,
    const float* __restrict__ bias2,
    const TR* __restrict__ resid, TO* __restrict__ out,
    bf16* __restrict__ vt, int M, int N, int K){
  constexpr int NW = BN/2, NF = NW/16, MI = (BM+31)/32, WRS = BM/2;
  constexpr int LOADS = BM/32 + BN/32;
  __shared__ char lA[2][BM*128];
  __shared__ char lB[2][BN*128];
  int tid = threadIdx.x, wave = tid>>6, lane = tid&63;
  int m0 = blockIdx.x*BM, n0 = blockIdx.y*BN;
  int wr = wave>>1, wc = wave&1;
  int g = lane>>4, li = lane&15;
  f32x4 acc[MI][NF] = {};
  stage_tile<256>(lA[0], A + (size_t)m0*K, K, BM, tid);
  stage_tile<256>(lB[0], WT + (size_t)n0*K, K, BN, tid);
  int NT = K>>6;
  int cur = 0;
  for(int t=0; t<NT; ++t, cur^=1){
    if(t+1 < NT){
      stage_tile<256>(lA[cur^1], A + (size_t)m0*K + (t+1)*64, K, BM, tid);
      stage_tile<256>(lB[cur^1], WT + (size_t)n0*K + (t+1)*64, K, BN, tid);
      waitcnt_vm<LOADS>();           // current tile landed; prefetch in flight
    } else {
      waitcnt_vm<0>();               // epilogue drain
    }
    __builtin_amdgcn_sched_barrier(0);
    __builtin_amdgcn_s_barrier();
    __builtin_amdgcn_sched_barrier(0);
#pragma unroll
    for(int kk=0; kk<2; kk++){
      s8v af[MI], bfr[NF];
#pragma unroll
      for(int mi=0;mi<MI;mi++) af[mi] = read_frag(lA[cur], wr*WRS+mi*16+li, kk*32+g*8);
#pragma unroll
      for(int ni=0;ni<NF;ni++) bfr[ni] = read_frag(lB[cur], wc*NW+ni*16+li, kk*32+g*8);
#pragma unroll
      for(int mi=0;mi<MI;mi++)
#pragma unroll
        for(int ni=0;ni<NF;ni++)
          acc[mi][ni] = MFMA_B16(af[mi], bfr[ni], acc[mi][ni]);
    }
    __builtin_amdgcn_sched_barrier(0);
    __builtin_amdgcn_s_barrier();    // reads done before buffer reuse
  }
#pragma unroll
  for(int mi=0;mi<MI;mi++)
#pragma unroll
  for(int ni=0;ni<NF;ni++){
    int row = m0 + wr*WRS + mi*16 + g*4;
    int col = n0 + wc*NW + ni*16 + li;
    const float* bp = bias0;
    if(QKVSEL) bp = (col<512)? bias0 : (col<1024)? (bias1-512) : (bias2-1024);
    float bb = bp[col];
    if(QKVSEL && col >= 1024){
      // V projection -> VT directly (k'-permuted); skip qkv write
      int hh = (col-1024)>>6, dd = (col-1024)&63;
      int b_ = row>>11, s = row&(NS-1);
      int kb_ = s&63;
      bf16* vtp = vt + (((size_t)(b_*NH+hh)*DKH + dd)*NS + (s&~63) + (kb_>>4));
#pragma unroll
      for(int r=0;r<4;r++)
        vtp[((kb_&15)+r)*4] = __float2bfloat16(acc[mi][ni][r] + bb);
      continue;
    }
#pragma unroll
    for(int r=0;r<4;r++){
      float v = acc[mi][ni][r] + bb;
      if(RELU) v = fmaxf(v, 0.f);
      size_t off = (size_t)(row+r)*N + col;
      if(resid) v += ldf(resid+off);
      stf(out+off, v);
    }
  }
}

// ---- Wo GEMM with fused split-K combine: A[m][h*64+d] = (pA+pB)*1/(lA+lB),
// computed on the fly during A-staging (each BK=64 k-tile == one head).
__global__ __launch_bounds__(256) void wo_gemm(
    const bf16* __restrict__ pA, const bf16* __restrict__ pB,
    const float* __restrict__ lbuf, const bf16* __restrict__ WTo,
    const float* __restrict__ bo, const float* __restrict__ xres,
    bf16* __restrict__ x1){
  __shared__ char lA[2][32*128];
  __shared__ char lB[2][64*128];
  int tid = threadIdx.x, wave = tid>>6, lane = tid&63;
  int m0 = blockIdx.x*32, n0 = blockIdx.y*64;
  int wr = wave>>1, wc = wave&1;
  int g = lane>>4, li = lane&15;
  f32x4 acc[2] = {};
  // fixed per-thread A chunk: row r in tile, source 8-col block blk (swizzle)
  int r = tid>>3, blk = (tid&7)^(r&7);
  int m = m0 + r, b_ = m>>11, q = m&(NS-1);

  auto cmb = [](unsigned int ua, unsigned int ub, float il) -> unsigned int {
    float lo = (us2f(ua&0xffffu)+us2f(ub&0xffffu))*il;
    float hi = (us2f(ua>>16)   +us2f(ub>>16)   )*il;
    return (unsigned int)f2bu(lo) | ((unsigned int)f2bu(hi)<<16);
  };
  auto stageA = [&](char* dst, int h){
    size_t base = (((size_t)(b_*NH+h)*NS) + q)*DKH + blk*8;
    uint4 a4 = *reinterpret_cast<const uint4*>(pA + base);
    uint4 b4 = *reinterpret_cast<const uint4*>(pB + base);
    float la = lbuf[((size_t)((b_*NH+h)*2+0))*NS + q];
    float lb = lbuf[((size_t)((b_*NH+h)*2+1))*NS + q];
    float il = 1.f/(la+lb);
    uint4 o;
    o.x = cmb(a4.x, b4.x, il);
    o.y = cmb(a4.y, b4.y, il);
    o.z = cmb(a4.z, b4.z, il);
    o.w = cmb(a4.w, b4.w, il);
    *reinterpret_cast<uint4*>(dst + tid*16) = o;
  };

  stageA(lA[0], 0);
  stage_tile<256>(lB[0], WTo + (size_t)n0*DM, DM, 64, tid);
  __syncthreads();
  int cur = 0;
  for(int t=0; t<8; ++t, cur^=1){
    if(t+1 < 8){
      stageA(lA[cur^1], t+1);
      stage_tile<256>(lB[cur^1], WTo + (size_t)n0*DM + (t+1)*64, DM, 64, tid);
    }
#pragma unroll
    for(int kk=0; kk<2; kk++){
      s8v af = read_frag(lA[cur], wr*16+li, kk*32+g*8);
      s8v b0 = read_frag(lB[cur], wc*32+li,    kk*32+g*8);
      s8v b1 = read_frag(lB[cur], wc*32+16+li, kk*32+g*8);
      acc[0] = MFMA_B16(af, b0, acc[0]);
      acc[1] = MFMA_B16(af, b1, acc[1]);
    }
    __syncthreads();
  }
  int row = m0 + wr*16 + g*4;
#pragma unroll
  for(int ni=0;ni<2;ni++){
    int col = n0 + wc*32 + ni*16 + li;
    float bv = bo[col];
#pragma unroll
    for(int r2=0;r2<4;r2++){
      size_t off = (size_t)(row+r2)*DM + col;
      x1[off] = __float2bfloat16(acc[ni][r2] + bv + xres[off]);
    }
  }
}

// ---- Flash attention: 512 thr / 8 waves / 128 q-rows, split-K, XCD swizzle.
// 128-wide k-tile per phase (two 64 sub-tiles per barrier pair).
// LDS 80KB -> 2 blocks/CU (grid 512 = exact fit, 16 waves/CU).
__global__ __launch_bounds__(512,2) void flash_attn(
    const bf16* __restrict__ QKV, const bf16* __restrict__ VT,
    const int* __restrict__ mask, bf16* __restrict__ partA,
    bf16* __restrict__ partB, float* __restrict__ lbuf){
  __shared__ char lK[2][128*128];     // 32 KB (128 k-rows x 64 d)
  __shared__ char lV[2][2][64*128];   // 32 KB (two 64-k sub-tiles x 64 d-rows)
  __shared__ char lP[8][16*128];      // 16 KB
  int tid = threadIdx.x, wave = tid>>6, lane = tid&63;
  // decode: xcd = bid&7; u = bid>>3; q-block(128) = u&15; bhk = xcd + 8*(u>>4)
  int bid = blockIdx.x;
  int xcd = bid & 7, u = bid >> 3;
  int q0 = (u & 15)*128;
  int bhk = xcd + 8*(u>>4);        // [0,32)
  int h = bhk & 7, kh = (bhk>>3)&1, b = bhk>>4;
  int kbase = kh*(NS/2);
  int g = lane>>4, li = lane&15;
  const bf16* Qg  = QKV + ((size_t)b*NS + q0)*LDQKV + h*DKH;
  const bf16* Kg  = QKV + ((size_t)b*NS + kbase)*LDQKV + DM + h*DKH;
  const bf16* VTg = VT + ((size_t)(b*NH + h))*DKH*NS + kbase;
  // Q (128 rows, 16KB) -> registers, staged through lK[0]
  stage_tile<512>(lK[0], Qg, LDQKV, 128, tid);
  __syncthreads();
  s8v qf0 = read_frag(lK[0], wave*16+li, g*8);
  s8v qf1 = read_frag(lK[0], wave*16+li, 32+g*8);
  __syncthreads();
  stage_tile<512>(lK[0], Kg, LDQKV, 128, tid);
  stage_tile<512>(lV[0][0], VTg,      NS, 64, tid);
  stage_tile<512>(lV[0][1], VTg + 64, NS, 64, tid);
  // per-lane mask bitmap: bit j = mask[kbase + j*16 + li]
  unsigned long long mb = 0;
#pragma unroll 16
  for(int j=0;j<64;j++)
    mb |= (unsigned long long)(mask[b*NS + kbase + j*16 + li] != 0) << j;
  __syncthreads();   // prologue drain (tile 0 + mask)
  f32x4 acc[4] = {};
  f32x4 acc_l = {};
  s8v ones;
#pragma unroll
  for(int j=0;j<8;j++) ones[j] = (short)0x3F80;   // bf16 1.0
  char* lPw = lP[wave];

  auto compute = [&](int t, int c){
#pragma unroll
    for(int s=0;s<2;s++){
      f32x4 S[4] = {};
      __builtin_amdgcn_s_setprio(1);
#pragma unroll
      for(int kk=0;kk<2;kk++){
        s8v qf = kk ? qf1 : qf0;
        s8v kf[4];
#pragma unroll
        for(int ni=0;ni<4;ni++) kf[ni] = read_frag(lK[c], s*64+ni*16+li, kk*32+g*8);
#pragma unroll
        for(int ni=0;ni<4;ni++)
          S[ni] = MFMA_B16(qf, kf[ni], S[ni]);
      }
      __builtin_amdgcn_s_setprio(0);
      int jb = t*8 + s*4;
      float madd[4];
#pragma unroll
      for(int ni=0;ni<4;ni++)
        madd[ni] = ((mb>>(jb+ni))&1ull) ? SM_SHIFT : NEG_BIG;
#pragma unroll
      for(int r=0;r<4;r++){
        float e0 = __expf(fmaf(S[0][r], 0.125f, madd[0]));
        float e1 = __expf(fmaf(S[1][r], 0.125f, madd[1]));
        float e2 = __expf(fmaf(S[2][r], 0.125f, madd[2]));
        float e3 = __expf(fmaf(S[3][r], 0.125f, madd[3]));
        int row = g*4 + r;
        uint2 w;
        w.x = (unsigned int)f2bu(e0) | ((unsigned int)f2bu(e1)<<16);
        w.y = (unsigned int)f2bu(e2) | ((unsigned int)f2bu(e3)<<16);
        *reinterpret_cast<uint2*>(lPw + swz(row, li<<3)) = w;   // k' = li*4..+3
      }
      __builtin_amdgcn_s_setprio(1);
#pragma unroll
      for(int kk=0;kk<2;kk++){
        s8v pf = read_frag(lPw, li, kk*32+g*8);
        s8v vf[4];
#pragma unroll
        for(int nd=0;nd<4;nd++) vf[nd] = read_frag(lV[c][s], nd*16+li, kk*32+g*8);
#pragma unroll
        for(int nd=0;nd<4;nd++)
          acc[nd] = MFMA_B16(pf, vf[nd], acc[nd]);
        acc_l = MFMA_B16(pf, ones, acc_l);
      }
      __builtin_amdgcn_s_setprio(0);
    }
  };

  int cur = 0;
  for(int t=0; t<7; ++t, cur^=1){
    stage_tile<512>(lK[cur^1], Kg + (size_t)(t+1)*128*LDQKV, LDQKV, 128, tid);
    stage_tile<512>(lV[cur^1][0], VTg + (t+1)*128,      NS, 64, tid);
    stage_tile<512>(lV[cur^1][1], VTg + (t+1)*128 + 64, NS, 64, tid);
    waitcnt_vm<4>();               // current tile landed; prefetch in flight
    __builtin_amdgcn_sched_barrier(0);
    __builtin_amdgcn_s_barrier();
    __builtin_amdgcn_sched_barrier(0);
    compute(t, cur);
    __builtin_amdgcn_sched_barrier(0);
    __builtin_amdgcn_s_barrier();  // reads done before buffer reuse
  }
  waitcnt_vm<0>();                 // epilogue drain (last tile)
  __builtin_amdgcn_sched_barrier(0);
  __builtin_amdgcn_s_barrier();
  __builtin_amdgcn_sched_barrier(0);
  compute(7, cur);

  bf16* part = kh ? partB : partA;
  size_t qb = (size_t)(b*NH + h)*NS;
#pragma unroll
  for(int r=0;r<4;r++){
    int qrow = q0 + wave*16 + g*4 + r;
#pragma unroll
    for(int nd=0;nd<4;nd++)
      part[(qb + qrow)*DKH + nd*16 + li] = __float2bfloat16(acc[nd][r]);
    if(li==0)
      lbuf[((size_t)((b*NH+h)*2 + kh))*NS + qrow] = acc_l[r];
  }
}

extern "C" void kernel_launch(void* const* d_in, const int* in_sizes, int n_in,
                              void* d_out, int out_size, void* d_ws, size_t ws_size,
                              hipStream_t stream){
  const float* x   = (const float*)d_in[0];
  const int* mask  = (const int*)d_in[1];
  const float* Wq = (const float*)d_in[2];
  const float* bq = (const float*)d_in[3];
  const float* Wk = (const float*)d_in[4];
  const float* bk = (const float*)d_in[5];
  const float* Wv = (const float*)d_in[6];
  const float* bv = (const float*)d_in[7];
  const float* Wo = (const float*)d_in[8];
  const float* bo = (const float*)d_in[9];
  const float* W1 = (const float*)d_in[10];
  const float* b1 = (const float*)d_in[11];
  const float* W2 = (const float*)d_in[12];
  const float* b2 = (const float*)d_in[13];
  const float* a1 = (const float*)d_in[14];
  const float* be1= (const float*)d_in[15];
  const float* a2 = (const float*)d_in[16];
  const float* be2= (const float*)d_in[17];

  // Workspace (28 MB):
  //  [ 0, 4M): h1 (LN1; dead after QKV) -> x1 (Wo out, live to end)
  //  [ 4,5.5M): WTqkv (dead after QKV) -> pA [4,8M) (flash partial A)
  //             -> h2 [4,8M) (LN2 out; pA dead after Wo)
  //  [ 8,10M): WT1 (dead after FFN1)   [10,12M): WT2 (live to FFN2)
  //  [12,24M): qkv (Q,K; dead after flash) -> mid [12,28M) at FFN1
  //  [24,28M): VT (dead after flash) -> mid tail
  // d_out scratch (8 MB, fully overwritten by FFN2):
  //  [0,256K): lbuf   [1M,5M): pB   [5M,5.5M): WTo
  char* ws = (char*)d_ws;
  bf16* h1    = (bf16*)(ws);
  bf16* x1    = (bf16*)(ws);
  bf16* WTqkv = (bf16*)(ws + (size_t)( 4<<20));
  bf16* pA    = (bf16*)(ws + (size_t)( 4<<20));
  bf16* h2    = (bf16*)(ws + (size_t)( 4<<20));
  bf16* WT1   = (bf16*)(ws + (size_t)( 8<<20));
  bf16* WT2   = (bf16*)(ws + (size_t)(10<<20));
  bf16* qkv   = (bf16*)(ws + (size_t)(12<<20));
  bf16* mid   = (bf16*)(ws + (size_t)(12<<20));
  bf16* VT    = (bf16*)(ws + (size_t)(24<<20));
  float* lbuf = (float*)d_out;
  bf16* pB    = (bf16*)((char*)d_out + (1<<20));
  bf16* WTo   = (bf16*)((char*)d_out + (5<<20));

  // prep: weight transposes (blocks 0..767) + LN1 (blocks 768..4863)
  prep_kernel<<<4864,256,0,stream>>>(Wq,Wk,Wv,Wo,W1,W2, WTqkv,WTo,WT1,WT2,
                                     x, h1, a1, be1);
  // fused QKV: Q,K -> qkv; V -> VT directly (k'-permuted)
  mfma_gemm<128,64,0,1,float,bf16><<<dim3(32,24),256,0,stream>>>(
      h1, WTqkv, bq, bk, bv, (const float*)nullptr, qkv, VT, NR, LDQKV, DM);
  flash_attn<<<512,512,0,stream>>>(qkv, VT, mask, pA, pB, lbuf);
  // Wo GEMM with fused split-K combine (no separate combine kernel)
  wo_gemm<<<dim3(128,8),256,0,stream>>>(pA, pB, lbuf, WTo, bo, x, x1);
  ln4_kernel<<<NR/4,256,0,stream>>>(x1, h2, a2, be2);
  mfma_gemm<128,128,1,0,float,bf16><<<dim3(32,16),256,0,stream>>>(
      h2, WT1, b1, b1, b1, (const float*)nullptr, mid, (bf16*)nullptr, NR, DFF, DM);
  mfma_gemm<32,128,0,0,bf16,float><<<dim3(128,4),256,0,stream>>>(
      mid, WT2, b2, b2, b2, x1, (float*)d_out, (bf16*)nullptr, NR, DM, DFF);
}

// Round 21
// 116.897 us; speedup vs baseline: 1.0519x; 1.0519x over previous
//
#include <hip/hip_runtime.h>
#include <hip/hip_bf16.h>

typedef __hip_bfloat16 bf16;
typedef __attribute__((ext_vector_type(8))) short s8v;
typedef __attribute__((ext_vector_type(4))) float f32x4;

#define DM 512
#define NH 8
#define DKH 64
#define DFF 2048
#define NB 2
#define NS 2048
#define NR (NB*NS)
#define LN_EPS 1e-6f
#define NEG_BIG (-1e30f)
#define LDQKV (3*DM)
// fixed-shift softmax (natural domain): P = exp(s*0.125 - 6), exact softmax
// numerator by shift-invariance; masked -> exp(-1e30) = 0.
#define SM_SHIFT (-6.0f)
#define PART_ELEMS (NB*NH*NS*DKH)    /* 2097152 */

#define MFMA_B16(a,b,c) __builtin_amdgcn_mfma_f32_16x16x32_bf16(a,b,c,0,0,0)

#define GLOAD16(g, l) __builtin_amdgcn_global_load_lds( \
    (const __attribute__((address_space(1))) void*)(g), \
    (__attribute__((address_space(3))) void*)(l), 16, 0, 0)

__device__ __forceinline__ float us2f(unsigned int u){ return __uint_as_float(u << 16); }
__device__ __forceinline__ float b2f(bf16 v){ return __bfloat162float(v); }
__device__ __forceinline__ float ldf(const float* p){ return *p; }
__device__ __forceinline__ float ldf(const bf16* p){ return __bfloat162float(*p); }
__device__ __forceinline__ void stf(float* p, float v){ *p = v; }
__device__ __forceinline__ void stf(bf16* p, float v){ *p = __float2bfloat16(v); }
__device__ __forceinline__ unsigned short f2bu(float f){
  bf16 b = __float2bfloat16(f);
  return *reinterpret_cast<unsigned short*>(&b);
}

template<int N> __device__ __forceinline__ void waitcnt_vm(){
  if constexpr(N==0)      asm volatile("s_waitcnt vmcnt(0)" ::: "memory");
  else if constexpr(N==2) asm volatile("s_waitcnt vmcnt(2)" ::: "memory");
  else if constexpr(N==3) asm volatile("s_waitcnt vmcnt(3)" ::: "memory");
  else if constexpr(N==4) asm volatile("s_waitcnt vmcnt(4)" ::: "memory");
  else if constexpr(N==5) asm volatile("s_waitcnt vmcnt(5)" ::: "memory");
  else if constexpr(N==6) asm volatile("s_waitcnt vmcnt(6)" ::: "memory");
  else if constexpr(N==8) asm volatile("s_waitcnt vmcnt(8)" ::: "memory");
}

// swizzled byte offset of element (row, col-byte) in a 128B-row LDS tile
__device__ __forceinline__ int swz(int row, int colbyte){
  return ((row<<7) + colbyte) ^ ((row&7)<<4);
}

__device__ __forceinline__ float wsum(float v){
#pragma unroll
  for(int o=32;o>0;o>>=1) v += __shfl_down(v,o,64);
  return v;
}

// ---- tile staging: R rows x 64 bf16 cols -> swizzled LDS.
// NTHR-generic: chunk c = tid + k*NTHR keeps wave-uniform base + lane*16.
template<int NTHR>
__device__ __forceinline__ void stage_tile(char* lds, const bf16* g, int ld, int R, int tid){
  int nch = R*8;
  for(int c = tid; c < nch; c += NTHR){
    int row = c>>3;
    int blk = (c&7) ^ (row&7);
    GLOAD16(g + (size_t)row*ld + blk*8, lds + c*16);
  }
}
__device__ __forceinline__ s8v read_frag(const char* lds, int row, int col){
  return *reinterpret_cast<const s8v*>(lds + swz(row, col<<1));
}

// ---- prep: batched weight transpose+convert (blocks 0..767) AND LN1
// (blocks 768..4863, one row each) in a single launch.
__global__ __launch_bounds__(256) void prep_kernel(
    const float* __restrict__ Wq, const float* __restrict__ Wk,
    const float* __restrict__ Wv, const float* __restrict__ Wo,
    const float* __restrict__ W1, const float* __restrict__ W2,
    bf16* __restrict__ WTqkv, bf16* __restrict__ WTo,
    bf16* __restrict__ WT1, bf16* __restrict__ WT2,
    const float* __restrict__ x, bf16* __restrict__ h1,
    const float* __restrict__ ap, const float* __restrict__ bp){
  __shared__ float t[64][65];
  __shared__ float s1[4], s2[4];
  int tid = threadIdx.x;
  if(blockIdx.x >= 768){
    // ---- LayerNorm row (unbiased var /511, eps added to std)
    int row = blockIdx.x - 768;
    const float* xr = x + (size_t)row*DM;
    float v0 = xr[tid], v1 = xr[tid+256];
    float s = wsum(v0+v1);
    float q = wsum(v0*v0+v1*v1);
    int wid = tid>>6, lane = tid&63;
    if(lane==0){ s1[wid]=s; s2[wid]=q; }
    __syncthreads();
    float S = s1[0]+s1[1]+s1[2]+s1[3];
    float Q = s2[0]+s2[1]+s2[2]+s2[3];
    float mean = S*(1.f/DM);
    float var  = (Q - (float)DM*mean*mean)*(1.f/(DM-1));
    float sd   = sqrtf(fmaxf(var,0.f));
    float sc = (*ap)/(sd+LN_EPS);
    float b = *bp;
    bf16* orow = h1 + (size_t)row*DM;
    orow[tid]     = __float2bfloat16((v0-mean)*sc + b);
    orow[tid+256] = __float2bfloat16((v1-mean)*sc + b);
    return;
  }
  int tb = blockIdx.x;
  const float* W; bf16* WT; int K, N, nx;
  if(tb < 192){
    int w = tb>>6; tb &= 63;
    W = (w==0)?Wq:(w==1)?Wk:Wv; WT = WTqkv + w*512*512; K=512; N=512; nx=8;
  } else if(tb < 256){ tb -= 192; W=Wo; WT=WTo; K=512; N=512; nx=8; }
  else if(tb < 512){ tb -= 256; W=W1; WT=WT1; K=512; N=2048; nx=32; }
  else { tb -= 512; W=W2; WT=WT2; K=2048; N=512; nx=8; }
  int n0 = (tb % nx)*64, k0 = (tb / nx)*64;
  int rr = tid>>6, cc = tid&63;
#pragma unroll
  for(int r=rr;r<64;r+=4) t[r][cc] = W[(size_t)(k0+r)*N + n0+cc];
  __syncthreads();
#pragma unroll
  for(int r=rr;r<64;r+=4) WT[(size_t)(n0+r)*K + k0+cc] = __float2bfloat16(t[cc][r]);
}

// ---- LayerNorm over bf16 rows, wave-per-row vectorized (16B load/store per lane)
__global__ __launch_bounds__(256) void ln4_kernel(const bf16* __restrict__ x,
    bf16* __restrict__ out, const float* __restrict__ ap, const float* __restrict__ bp){
  int tid = threadIdx.x, wave = tid>>6, lane = tid&63;
  int row = blockIdx.x*4 + wave;
  const bf16* xr = x + (size_t)row*DM + lane*8;
  s8v v = *reinterpret_cast<const s8v*>(xr);
  float f[8];
  float s = 0.f, q = 0.f;
#pragma unroll
  for(int j=0;j<8;j++){
    f[j] = us2f((unsigned short)v[j]);
    s += f[j]; q += f[j]*f[j];
  }
  s = wsum(s); q = wsum(q);
  s = __shfl(s, 0, 64); q = __shfl(q, 0, 64);
  float mean = s*(1.f/DM);
  float var  = (q - (float)DM*mean*mean)*(1.f/(DM-1));
  float sd   = sqrtf(fmaxf(var,0.f));
  float sc = (*ap)/(sd+LN_EPS);
  float b = *bp;
  s8v o;
#pragma unroll
  for(int j=0;j<8;j++) o[j] = (short)f2bu((f[j]-mean)*sc + b);
  *reinterpret_cast<s8v*>(out + (size_t)row*DM + lane*8) = o;
}

// ---- MFMA GEMM: C[m][n] = A[m][k] * WT[n][k] + bias (+resid) (+relu)
// 4 waves, tile BM x BN, BK=64, dbuf LDS + counted vmcnt (never drain mid-loop).
// QKVSEL=1: cols [1024,1536) (the V projection) are written DIRECTLY to
// VT [b][h][d][k'] with the k-permutation kp=((k&15)+r)*4+(k>>4).
template<int BM, int BN, int RELU, int QKVSEL, typename TR, typename TO>
__global__ __launch_bounds__(256) void mfma_gemm(
    const bf16* __restrict__ A, const bf16* __restrict__ WT,
    const float* __restrict__ bias0, const float* __restrict__ bias1,
    const float* __restrict__ bias2,
    const TR* __restrict__ resid, TO* __restrict__ out,
    bf16* __restrict__ vt, int M, int N, int K){
  constexpr int NW = BN/2, NF = NW/16, MI = (BM+31)/32, WRS = BM/2;
  constexpr int LOADS = BM/32 + BN/32;
  __shared__ char lA[2][BM*128];
  __shared__ char lB[2][BN*128];
  int tid = threadIdx.x, wave = tid>>6, lane = tid&63;
  int m0 = blockIdx.x*BM, n0 = blockIdx.y*BN;
  int wr = wave>>1, wc = wave&1;
  int g = lane>>4, li = lane&15;
  f32x4 acc[MI][NF] = {};
  stage_tile<256>(lA[0], A + (size_t)m0*K, K, BM, tid);
  stage_tile<256>(lB[0], WT + (size_t)n0*K, K, BN, tid);
  int NT = K>>6;
  int cur = 0;
  for(int t=0; t<NT; ++t, cur^=1){
    if(t+1 < NT){
      stage_tile<256>(lA[cur^1], A + (size_t)m0*K + (t+1)*64, K, BM, tid);
      stage_tile<256>(lB[cur^1], WT + (size_t)n0*K + (t+1)*64, K, BN, tid);
      waitcnt_vm<LOADS>();           // current tile landed; prefetch in flight
    } else {
      waitcnt_vm<0>();               // epilogue drain
    }
    __builtin_amdgcn_sched_barrier(0);
    __builtin_amdgcn_s_barrier();
    __builtin_amdgcn_sched_barrier(0);
#pragma unroll
    for(int kk=0; kk<2; kk++){
      s8v af[MI], bfr[NF];
#pragma unroll
      for(int mi=0;mi<MI;mi++) af[mi] = read_frag(lA[cur], wr*WRS+mi*16+li, kk*32+g*8);
#pragma unroll
      for(int ni=0;ni<NF;ni++) bfr[ni] = read_frag(lB[cur], wc*NW+ni*16+li, kk*32+g*8);
#pragma unroll
      for(int mi=0;mi<MI;mi++)
#pragma unroll
        for(int ni=0;ni<NF;ni++)
          acc[mi][ni] = MFMA_B16(af[mi], bfr[ni], acc[mi][ni]);
    }
    __builtin_amdgcn_sched_barrier(0);
    __builtin_amdgcn_s_barrier();    // reads done before buffer reuse
  }
#pragma unroll
  for(int mi=0;mi<MI;mi++)
#pragma unroll
  for(int ni=0;ni<NF;ni++){
    int row = m0 + wr*WRS + mi*16 + g*4;
    int col = n0 + wc*NW + ni*16 + li;
    const float* bp = bias0;
    if(QKVSEL) bp = (col<512)? bias0 : (col<1024)? (bias1-512) : (bias2-1024);
    float bb = bp[col];
    if(QKVSEL && col >= 1024){
      // V projection -> VT directly (k'-permuted); skip qkv write
      int hh = (col-1024)>>6, dd = (col-1024)&63;
      int b_ = row>>11, s = row&(NS-1);
      int kb_ = s&63;
      bf16* vtp = vt + (((size_t)(b_*NH+hh)*DKH + dd)*NS + (s&~63) + (kb_>>4));
#pragma unroll
      for(int r=0;r<4;r++)
        vtp[((kb_&15)+r)*4] = __float2bfloat16(acc[mi][ni][r] + bb);
      continue;
    }
#pragma unroll
    for(int r=0;r<4;r++){
      float v = acc[mi][ni][r] + bb;
      if(RELU) v = fmaxf(v, 0.f);
      size_t off = (size_t)(row+r)*N + col;
      if(resid) v += ldf(resid+off);
      stf(out+off, v);
    }
  }
}

// ---- Wo GEMM with fused split-K combine: A[m][h*64+d] = (pA+pB)*1/(lA+lB),
// computed on the fly during A-staging (each BK=64 k-tile == one head).
__global__ __launch_bounds__(256) void wo_gemm(
    const bf16* __restrict__ pA, const bf16* __restrict__ pB,
    const float* __restrict__ lbuf, const bf16* __restrict__ WTo,
    const float* __restrict__ bo, const float* __restrict__ xres,
    bf16* __restrict__ x1){
  __shared__ char lA[2][32*128];
  __shared__ char lB[2][64*128];
  int tid = threadIdx.x, wave = tid>>6, lane = tid&63;
  int m0 = blockIdx.x*32, n0 = blockIdx.y*64;
  int wr = wave>>1, wc = wave&1;
  int g = lane>>4, li = lane&15;
  f32x4 acc[2] = {};
  // fixed per-thread A chunk: row r in tile, source 8-col block blk (swizzle)
  int r = tid>>3, blk = (tid&7)^(r&7);
  int m = m0 + r, b_ = m>>11, q = m&(NS-1);

  auto cmb = [](unsigned int ua, unsigned int ub, float il) -> unsigned int {
    float lo = (us2f(ua&0xffffu)+us2f(ub&0xffffu))*il;
    float hi = (us2f(ua>>16)   +us2f(ub>>16)   )*il;
    return (unsigned int)f2bu(lo) | ((unsigned int)f2bu(hi)<<16);
  };
  auto stageA = [&](char* dst, int h){
    size_t base = (((size_t)(b_*NH+h)*NS) + q)*DKH + blk*8;
    uint4 a4 = *reinterpret_cast<const uint4*>(pA + base);
    uint4 b4 = *reinterpret_cast<const uint4*>(pB + base);
    float la = lbuf[((size_t)((b_*NH+h)*2+0))*NS + q];
    float lb = lbuf[((size_t)((b_*NH+h)*2+1))*NS + q];
    float il = 1.f/(la+lb);
    uint4 o;
    o.x = cmb(a4.x, b4.x, il);
    o.y = cmb(a4.y, b4.y, il);
    o.z = cmb(a4.z, b4.z, il);
    o.w = cmb(a4.w, b4.w, il);
    *reinterpret_cast<uint4*>(dst + tid*16) = o;
  };

  stageA(lA[0], 0);
  stage_tile<256>(lB[0], WTo + (size_t)n0*DM, DM, 64, tid);
  __syncthreads();
  int cur = 0;
  for(int t=0; t<8; ++t, cur^=1){
    if(t+1 < 8){
      stageA(lA[cur^1], t+1);
      stage_tile<256>(lB[cur^1], WTo + (size_t)n0*DM + (t+1)*64, DM, 64, tid);
    }
#pragma unroll
    for(int kk=0; kk<2; kk++){
      s8v af = read_frag(lA[cur], wr*16+li, kk*32+g*8);
      s8v b0 = read_frag(lB[cur], wc*32+li,    kk*32+g*8);
      s8v b1 = read_frag(lB[cur], wc*32+16+li, kk*32+g*8);
      acc[0] = MFMA_B16(af, b0, acc[0]);
      acc[1] = MFMA_B16(af, b1, acc[1]);
    }
    __syncthreads();
  }
  int row = m0 + wr*16 + g*4;
#pragma unroll
  for(int ni=0;ni<2;ni++){
    int col = n0 + wc*32 + ni*16 + li;
    float bv = bo[col];
#pragma unroll
    for(int r2=0;r2<4;r2++){
      size_t off = (size_t)(row+r2)*DM + col;
      x1[off] = __float2bfloat16(acc[ni][r2] + bv + xres[off]);
    }
  }
}

// ---- Flash attention: 512 thr / 8 waves / 128 q-rows, split-K, XCD swizzle.
// 128-wide k-tile per phase (two 64 sub-tiles per barrier pair).
// LDS 80KB -> 2 blocks/CU (grid 512 = exact fit, 16 waves/CU).
__global__ __launch_bounds__(512,2) void flash_attn(
    const bf16* __restrict__ QKV, const bf16* __restrict__ VT,
    const int* __restrict__ mask, bf16* __restrict__ partA,
    bf16* __restrict__ partB, float* __restrict__ lbuf){
  __shared__ char lK[2][128*128];     // 32 KB (128 k-rows x 64 d)
  __shared__ char lV[2][2][64*128];   // 32 KB (two 64-k sub-tiles x 64 d-rows)
  __shared__ char lP[8][16*128];      // 16 KB
  int tid = threadIdx.x, wave = tid>>6, lane = tid&63;
  // decode: xcd = bid&7; u = bid>>3; q-block(128) = u&15; bhk = xcd + 8*(u>>4)
  int bid = blockIdx.x;
  int xcd = bid & 7, u = bid >> 3;
  int q0 = (u & 15)*128;
  int bhk = xcd + 8*(u>>4);        // [0,32)
  int h = bhk & 7, kh = (bhk>>3)&1, b = bhk>>4;
  int kbase = kh*(NS/2);
  int g = lane>>4, li = lane&15;
  const bf16* Qg  = QKV + ((size_t)b*NS + q0)*LDQKV + h*DKH;
  const bf16* Kg  = QKV + ((size_t)b*NS + kbase)*LDQKV + DM + h*DKH;
  const bf16* VTg = VT + ((size_t)(b*NH + h))*DKH*NS + kbase;
  // Q (128 rows, 16KB) -> registers, staged through lK[0]
  stage_tile<512>(lK[0], Qg, LDQKV, 128, tid);
  __syncthreads();
  s8v qf0 = read_frag(lK[0], wave*16+li, g*8);
  s8v qf1 = read_frag(lK[0], wave*16+li, 32+g*8);
  __syncthreads();
  stage_tile<512>(lK[0], Kg, LDQKV, 128, tid);
  stage_tile<512>(lV[0][0], VTg,      NS, 64, tid);
  stage_tile<512>(lV[0][1], VTg + 64, NS, 64, tid);
  // per-lane mask bitmap: bit j = mask[kbase + j*16 + li]
  unsigned long long mb = 0;
#pragma unroll 16
  for(int j=0;j<64;j++)
    mb |= (unsigned long long)(mask[b*NS + kbase + j*16 + li] != 0) << j;
  __syncthreads();   // prologue drain (tile 0 + mask)
  f32x4 acc[4] = {};
  f32x4 acc_l = {};
  s8v ones;
#pragma unroll
  for(int j=0;j<8;j++) ones[j] = (short)0x3F80;   // bf16 1.0
  char* lPw = lP[wave];

  auto compute = [&](int t, int c){
#pragma unroll
    for(int s=0;s<2;s++){
      f32x4 S[4] = {};
      __builtin_amdgcn_s_setprio(1);
#pragma unroll
      for(int kk=0;kk<2;kk++){
        s8v qf = kk ? qf1 : qf0;
        s8v kf[4];
#pragma unroll
        for(int ni=0;ni<4;ni++) kf[ni] = read_frag(lK[c], s*64+ni*16+li, kk*32+g*8);
#pragma unroll
        for(int ni=0;ni<4;ni++)
          S[ni] = MFMA_B16(qf, kf[ni], S[ni]);
      }
      __builtin_amdgcn_s_setprio(0);
      int jb = t*8 + s*4;
      float madd[4];
#pragma unroll
      for(int ni=0;ni<4;ni++)
        madd[ni] = ((mb>>(jb+ni))&1ull) ? SM_SHIFT : NEG_BIG;
#pragma unroll
      for(int r=0;r<4;r++){
        float e0 = __expf(fmaf(S[0][r], 0.125f, madd[0]));
        float e1 = __expf(fmaf(S[1][r], 0.125f, madd[1]));
        float e2 = __expf(fmaf(S[2][r], 0.125f, madd[2]));
        float e3 = __expf(fmaf(S[3][r], 0.125f, madd[3]));
        int row = g*4 + r;
        uint2 w;
        w.x = (unsigned int)f2bu(e0) | ((unsigned int)f2bu(e1)<<16);
        w.y = (unsigned int)f2bu(e2) | ((unsigned int)f2bu(e3)<<16);
        *reinterpret_cast<uint2*>(lPw + swz(row, li<<3)) = w;   // k' = li*4..+3
      }
      __builtin_amdgcn_s_setprio(1);
#pragma unroll
      for(int kk=0;kk<2;kk++){
        s8v pf = read_frag(lPw, li, kk*32+g*8);
        s8v vf[4];
#pragma unroll
        for(int nd=0;nd<4;nd++) vf[nd] = read_frag(lV[c][s], nd*16+li, kk*32+g*8);
#pragma unroll
        for(int nd=0;nd<4;nd++)
          acc[nd] = MFMA_B16(pf, vf[nd], acc[nd]);
        acc_l = MFMA_B16(pf, ones, acc_l);
      }
      __builtin_amdgcn_s_setprio(0);
    }
  };

  int cur = 0;
  for(int t=0; t<7; ++t, cur^=1){
    stage_tile<512>(lK[cur^1], Kg + (size_t)(t+1)*128*LDQKV, LDQKV, 128, tid);
    stage_tile<512>(lV[cur^1][0], VTg + (t+1)*128,      NS, 64, tid);
    stage_tile<512>(lV[cur^1][1], VTg + (t+1)*128 + 64, NS, 64, tid);
    waitcnt_vm<4>();               // current tile landed; prefetch in flight
    __builtin_amdgcn_sched_barrier(0);
    __builtin_amdgcn_s_barrier();
    __builtin_amdgcn_sched_barrier(0);
    compute(t, cur);
    __builtin_amdgcn_sched_barrier(0);
    __builtin_amdgcn_s_barrier();  // reads done before buffer reuse
  }
  waitcnt_vm<0>();                 // epilogue drain (last tile)
  __builtin_amdgcn_sched_barrier(0);
  __builtin_amdgcn_s_barrier();
  __builtin_amdgcn_sched_barrier(0);
  compute(7, cur);

  bf16* part = kh ? partB : partA;
  size_t qb = (size_t)(b*NH + h)*NS;
#pragma unroll
  for(int r=0;r<4;r++){
    int qrow = q0 + wave*16 + g*4 + r;
#pragma unroll
    for(int nd=0;nd<4;nd++)
      part[(qb + qrow)*DKH + nd*16 + li] = __float2bfloat16(acc[nd][r]);
    if(li==0)
      lbuf[((size_t)((b*NH+h)*2 + kh))*NS + qrow] = acc_l[r];
  }
}

extern "C" void kernel_launch(void* const* d_in, const int* in_sizes, int n_in,
                              void* d_out, int out_size, void* d_ws, size_t ws_size,
                              hipStream_t stream){
  const float* x   = (const float*)d_in[0];
  const int* mask  = (const int*)d_in[1];
  const float* Wq = (const float*)d_in[2];
  const float* bq = (const float*)d_in[3];
  const float* Wk = (const float*)d_in[4];
  const float* bk = (const float*)d_in[5];
  const float* Wv = (const float*)d_in[6];
  const float* bv = (const float*)d_in[7];
  const float* Wo = (const float*)d_in[8];
  const float* bo = (const float*)d_in[9];
  const float* W1 = (const float*)d_in[10];
  const float* b1 = (const float*)d_in[11];
  const float* W2 = (const float*)d_in[12];
  const float* b2 = (const float*)d_in[13];
  const float* a1 = (const float*)d_in[14];
  const float* be1= (const float*)d_in[15];
  const float* a2 = (const float*)d_in[16];
  const float* be2= (const float*)d_in[17];

  // Workspace (28 MB):
  //  [ 0, 4M): h1 (LN1; dead after QKV) -> x1 (Wo out, live to end)
  //  [ 4,5.5M): WTqkv (dead after QKV) -> pA [4,8M) (flash partial A)
  //             -> h2 [4,8M) (LN2 out; pA dead after Wo)
  //  [ 8,10M): WT1 (dead after FFN1)   [10,12M): WT2 (live to FFN2)
  //  [12,24M): qkv (Q,K; dead after flash) -> mid [12,28M) at FFN1
  //  [24,28M): VT (dead after flash) -> mid tail
  // d_out scratch (8 MB, fully overwritten by FFN2):
  //  [0,256K): lbuf   [1M,5M): pB   [5M,5.5M): WTo
  char* ws = (char*)d_ws;
  bf16* h1    = (bf16*)(ws);
  bf16* x1    = (bf16*)(ws);
  bf16* WTqkv = (bf16*)(ws + (size_t)( 4<<20));
  bf16* pA    = (bf16*)(ws + (size_t)( 4<<20));
  bf16* h2    = (bf16*)(ws + (size_t)( 4<<20));
  bf16* WT1   = (bf16*)(ws + (size_t)( 8<<20));
  bf16* WT2   = (bf16*)(ws + (size_t)(10<<20));
  bf16* qkv   = (bf16*)(ws + (size_t)(12<<20));
  bf16* mid   = (bf16*)(ws + (size_t)(12<<20));
  bf16* VT    = (bf16*)(ws + (size_t)(24<<20));
  float* lbuf = (float*)d_out;
  bf16* pB    = (bf16*)((char*)d_out + (1<<20));
  bf16* WTo   = (bf16*)((char*)d_out + (5<<20));

  // prep: weight transposes (blocks 0..767) + LN1 (blocks 768..4863)
  prep_kernel<<<4864,256,0,stream>>>(Wq,Wk,Wv,Wo,W1,W2, WTqkv,WTo,WT1,WT2,
                                     x, h1, a1, be1);
  // fused QKV: Q,K -> qkv; V -> VT directly (k'-permuted)
  mfma_gemm<128,64,0,1,float,bf16><<<dim3(32,24),256,0,stream>>>(
      h1, WTqkv, bq, bk, bv, (const float*)nullptr, qkv, VT, NR, LDQKV, DM);
  flash_attn<<<512,512,0,stream>>>(qkv, VT, mask, pA, pB, lbuf);
  // Wo GEMM with fused split-K combine (no separate combine kernel)
  wo_gemm<<<dim3(128,8),256,0,stream>>>(pA, pB, lbuf, WTo, bo, x, x1);
  ln4_kernel<<<NR/4,256,0,stream>>>(x1, h2, a2, be2);
  mfma_gemm<128,128,1,0,float,bf16><<<dim3(32,16),256,0,stream>>>(
      h2, WT1, b1, b1, b1, (const float*)nullptr, mid, (bf16*)nullptr, NR, DFF, DM);
  mfma_gemm<32,64,0,0,bf16,float><<<dim3(128,8),256,0,stream>>>(
      mid, WT2, b2, b2, b2, x1, (float*)d_out, (bf16*)nullptr, NR, DM, DFF);
}